// Round 1
// 165.115 us; speedup vs baseline: 1.0037x; 1.0037x over previous
//
#include <hip/hip_runtime.h>

// DDLG autoencoder, fully fused, batch-tile 4, ALL-fp16 packed compute.
//   out[b][o] = sum_f prob[o][f] * op_f(x[b][idx[o][0..7]])
// R1: divide-free Einstein reductions via homomorphisms:
//     ein-product = 2D/(N+D),  D=prod(f), N=prod(2-f)
//     ein-sum     = (N-D)/(N+D), N=prod(1+f), D=prod(1-f)
// R5: 48 KB LDS, 1024-thr blocks, 2 blocks/CU; conflict-free staging.
// R6: chains/min/max/finale in packed fp16 (v_pk_*_f16, 2 elems/inst).
// R7 (this round):
//   - rolling GatePre prefetch: idx+probs of gate i+1 issued before gate i's
//     chain; loads placed before a __syncthreads drain for free at the barrier.
//     Kills the L2-latency stall at the head of every gate (VALUBusy 60%->?).
//   - idxS removed: the <<2 pre-scale folds into the ds addressing shift
//     (v_lshl_add x8 instead of x2, same inst count). prep_k is probs-only
//     (36 blocks), workspace idx traffic gone.
//     LDS overlays (fp16 rows of 4 = 8 B, ds_read_b64 gathers):
//       x @ [0,16384) | h0 @ [16384,24576) | h1 @ [0,4096) | h2 @ [16384,24576)

#define BATCH 4096

typedef _Float16 h4 __attribute__((ext_vector_type(4)));

__device__ __forceinline__ float fastrcp(float x) { return __builtin_amdgcn_rcpf(x); }
__device__ __forceinline__ _Float16 hrcp(_Float16 x) {
#if __has_builtin(__builtin_amdgcn_rcph)
    return __builtin_amdgcn_rcph(x);
#else
    return (_Float16)__builtin_amdgcn_rcpf((float)x);
#endif
}
__device__ __forceinline__ h4 splat(_Float16 s) { h4 v = {s, s, s, s}; return v; }

// ---------------- prep: fp16 prob table only ----------------
// probsH: [0,2048) L0 | [2048,3072) L1 | [3072,5120) L2 | [5120,9216) L3
__global__ __launch_bounds__(256) void prep_k(const float* __restrict__ w0,
                                              const float* __restrict__ w1,
                                              const float* __restrict__ w2,
                                              const float* __restrict__ w3,
                                              const int* __restrict__ is_train,
                                              h4* __restrict__ probsH) {
    const int g = blockIdx.x * 256 + threadIdx.x;   // grid 36 -> 9216 exact
    const float* w; int o;
    if (g < 2048)      { w = w0; o = g; }
    else if (g < 3072) { w = w1; o = g - 2048; }
    else if (g < 5120) { w = w2; o = g - 3072; }
    else               { w = w3; o = g - 5120; }
    float wv[4];
#pragma unroll
    for (int c = 0; c < 4; ++c) wv[c] = w[(o << 2) + c];
    float p[4];
    if (*is_train) {
        float m = fmaxf(fmaxf(wv[0], wv[1]), fmaxf(wv[2], wv[3]));
        float s = 0.0f;
#pragma unroll
        for (int c = 0; c < 4; ++c) { p[c] = __expf(wv[c] - m); s += p[c]; }
        float inv = fastrcp(s);
#pragma unroll
        for (int c = 0; c < 4; ++c) p[c] *= inv;
    } else {
        int a = 0; float best = wv[0];
#pragma unroll
        for (int c = 1; c < 4; ++c) if (wv[c] > best) { best = wv[c]; a = c; }
#pragma unroll
        for (int c = 0; c < 4; ++c) p[c] = (c == a) ? 1.0f : 0.0f;
    }
    probsH[g] = h4{(_Float16)p[0], (_Float16)p[1], (_Float16)p[2], (_Float16)p[3]};
}

// ---------------- prefetched gate state: 10 VGPRs ----------------
struct GatePre { int4 i0, i1; h4 P; };

__device__ __forceinline__ GatePre pre_load(const int4* __restrict__ idx,
                                            const h4* __restrict__ probs, int o) {
    GatePre g;
    g.i0 = idx[o * 2];
    g.i1 = idx[o * 2 + 1];
    g.P  = probs[o];
    return g;
}

// ---------------- one output o, 4 batch lanes, all fp16 ----------------
// rows = LDS activation table viewed as 8 B h4 rows (row j = activations of
// feature j for the 4 batch lanes). Raw idx -> byte offset = idx*8 (one
// v_lshl_add, same cost as the old pre-scaled form).
__device__ __forceinline__ h4 gate_body(const h4* __restrict__ rows, const GatePre g) {
    h4 raw[8];
    raw[0] = rows[g.i0.x];
    raw[1] = rows[g.i0.y];
    raw[2] = rows[g.i0.z];
    raw[3] = rows[g.i0.w];
    raw[4] = rows[g.i1.x];
    raw[5] = rows[g.i1.y];
    raw[6] = rows[g.i1.z];
    raw[7] = rows[g.i1.w];

    const h4 one = splat((_Float16)1.0f);
    const h4 two = splat((_Float16)2.0f);

    h4 mn = raw[0], mx = raw[0], De = raw[0];
    h4 Ne = two - raw[0];
    h4 Nc = one + raw[0];
    h4 Dc = one - raw[0];
#pragma unroll
    for (int c = 1; c < 8; ++c) {
        h4 v = raw[c];
        mn = __builtin_elementwise_min(mn, v);
        mx = __builtin_elementwise_max(mx, v);
        De *= v;
        Ne *= (two - v);
        Nc += Nc * v;   // pk_fma: Nc *= (1+v)
        Dc -= Dc * v;   // pk_fma: Dc *= (1-v)
    }
    h4 s1 = Ne + De;    // in [1, 257]: fp16-safe
    h4 s2 = Nc + Dc;    // in [1, 257]
    h4 d1 = Nc - Dc;
    h4 r1, r2;
#pragma unroll
    for (int e = 0; e < 4; ++e) { r1[e] = hrcp(s1[e]); r2[e] = hrcp(s2[e]); }
    h4 ein = (De + De) * r1;
    h4 coe = d1 * r2;
    h4 res = splat(g.P[0]) * mn;
    res += splat(g.P[1]) * mx;
    res += splat(g.P[2]) * ein;
    res += splat(g.P[3]) * coe;
    return res;
}

// ---------------- the fused network ----------------
// grid = 1024 (one block per 4-batch tile), block = 1024, 2 blocks/CU
__global__ __launch_bounds__(1024, 8) void ddlg_fused(const float* __restrict__ x,
                                                      const h4* __restrict__ probsH,
                                                      const int4* __restrict__ idx0,
                                                      const int4* __restrict__ idx1,
                                                      const int4* __restrict__ idx2,
                                                      const int4* __restrict__ idx3,
                                                      float* __restrict__ out) {
    __shared__ __align__(16) _Float16 lds[24576];   // 48 KB
    const int t  = threadIdx.x;
    const int b0 = blockIdx.x << 2;

    const h4* xl = (const h4*)lds;                  // rows [0,4096)
    const h4* h0 = (const h4*)(lds + 16384);        // rows [0,2048)
    const h4* h1 = (const h4*)lds;                  // rows [0,1024) (over dead x)
    const h4* h2 = (const h4*)(lds + 16384);        // rows [0,2048) (over dead h0)

    // ---- prefetch L0's two gates first: loads in flight across staging,
    //      drained for free by the barrier's vmcnt(0) ----
    GatePre gA = pre_load(idx0, probsH, t);
    GatePre gB = pre_load(idx0, probsH, t + 1024);

    // ---- stage x columns: thread owns j; 4 coalesced scalar loads -> b64 row ----
#pragma unroll
    for (int c = 0; c < 4; ++c) {
        const int j = (c << 10) + t;
        const float v0 = x[(size_t)(b0 + 0) * 4096 + j];
        const float v1 = x[(size_t)(b0 + 1) * 4096 + j];
        const float v2 = x[(size_t)(b0 + 2) * 4096 + j];
        const float v3 = x[(size_t)(b0 + 3) * 4096 + j];
        h4 hv;
        hv[0] = (_Float16)v0; hv[1] = (_Float16)v1;
        hv[2] = (_Float16)v2; hv[3] = (_Float16)v3;
        *(h4*)(lds + (j << 2)) = hv;    // stride-1 ds_write_b64: conflict-free
    }
    __syncthreads();

    // ---- L0: 4096 -> 2048 (2 gates; prefetch L1/L2 heads between them) ----
    {
        h4 r = gate_body(xl, gA);
        gA = pre_load(idx1, probsH + 2048, t);            // L1.g0 prefetch
        *(h4*)(lds + 16384 + (t << 2)) = r;
        r = gate_body(xl, gB);
        gB = pre_load(idx2, probsH + 3072, t);            // L2.g0 prefetch
        *(h4*)(lds + 16384 + ((t + 1024) << 2)) = r;
    }
    __syncthreads();

    // ---- L1: 2048 -> 1024 ----
    {
        h4 r = gate_body(h0, gA);
        gA = pre_load(idx2, probsH + 3072, t + 1024);     // L2.g1 prefetch
        *(h4*)(lds + (t << 2)) = r;
    }
    __syncthreads();

    // ---- L2: 1024 -> 2048 ----
    {
        h4 r = gate_body(h1, gB);
        gB = pre_load(idx3, probsH + 5120, t);            // L3.g0 prefetch
        *(h4*)(lds + 16384 + (t << 2)) = r;
        r = gate_body(h1, gA);
        gA = pre_load(idx3, probsH + 5120, t + 1024);     // L3.g1 prefetch
        *(h4*)(lds + 16384 + ((t + 1024) << 2)) = r;
    }
    __syncthreads();

    // ---- L3: 2048 -> 4096, rolling depth-2 prefetch, direct global store
    //      (lanes sweep o: coalesced dword stores) ----
    {
        h4 r = gate_body(h2, gB);
        gB = pre_load(idx3, probsH + 5120, t + 2048);     // L3.g2 prefetch
#pragma unroll
        for (int b = 0; b < 4; ++b)
            out[(size_t)(b0 + b) * 4096 + t] = (float)r[b];

        r = gate_body(h2, gA);
        gA = pre_load(idx3, probsH + 5120, t + 3072);     // L3.g3 prefetch
#pragma unroll
        for (int b = 0; b < 4; ++b)
            out[(size_t)(b0 + b) * 4096 + (t + 1024)] = (float)r[b];

        r = gate_body(h2, gB);
#pragma unroll
        for (int b = 0; b < 4; ++b)
            out[(size_t)(b0 + b) * 4096 + (t + 2048)] = (float)r[b];

        r = gate_body(h2, gA);
#pragma unroll
        for (int b = 0; b < 4; ++b)
            out[(size_t)(b0 + b) * 4096 + (t + 3072)] = (float)r[b];
    }
}

extern "C" void kernel_launch(void* const* d_in, const int* in_sizes, int n_in,
                              void* d_out, int out_size, void* d_ws, size_t ws_size,
                              hipStream_t stream) {
    const float* x        = (const float*)d_in[0];
    const float* w0       = (const float*)d_in[1];
    const float* w1       = (const float*)d_in[2];
    const float* w2       = (const float*)d_in[3];
    const float* w3       = (const float*)d_in[4];
    const int4*  idx0     = (const int4*)d_in[5];
    const int4*  idx1     = (const int4*)d_in[6];
    const int4*  idx2     = (const int4*)d_in[7];
    const int4*  idx3     = (const int4*)d_in[8];
    const int*   is_train = (const int*)d_in[9];
    float*       out      = (float*)d_out;

    // ws: probsH 9216*8B = 72 KB @0
    h4* probsH = (h4*)d_ws;

    prep_k<<<36, 256, 0, stream>>>(w0, w1, w2, w3, is_train, probsH);
    ddlg_fused<<<1024, 1024, 0, stream>>>(x, probsH, idx0, idx1, idx2, idx3, out);
}

// Round 2
// 164.153 us; speedup vs baseline: 1.0096x; 1.0059x over previous
//
#include <hip/hip_runtime.h>

// DDLG autoencoder, fully fused, batch-tile 4, ALL-fp16 packed compute.
//   out[b][o] = sum_f prob[o][f] * op_f(x[b][idx[o][0..7]])
// R1: divide-free Einstein reductions via homomorphisms:
//     ein-product = 2D/(N+D),  D=prod(f), N=prod(2-f)
//     ein-sum     = (N-D)/(N+D), N=prod(1+f), D=prod(1-f)
// R5: 48 KB LDS, 1024-thr blocks, 2 blocks/CU; conflict-free staging.
// R6: chains/min/max/finale in packed fp16 (v_pk_*_f16, 2 elems/inst).
// R7: idx pre-scale folded into addressing; prep_k is probs-only.
// R8 (this round):
//   - combined-denominator finale: ein+coe share one rcp over s1*s2.
//     Range proof: s1*s2 <= prod((2-f)(1+f)) + s1 + s2 <= 2.25^8 + 257 ~ 914,
//     numerators 2De*s2 <= 514, d1*s1 <= 912 -- all fp16-safe. rcps 8 -> 4/gate.
//   - consecutive-o ownership: L0/L2 thread owns o=2t,2t+1 (paired gates,
//     interleaved chains for 2x ILP, one b128 LDS result write); L3 owns
//     o=4t..4t+3 (two pairs, float4 output stores: 16 stores -> 4).
//     LDS overlays (fp16 rows of 4 = 8 B, ds_read_b64 gathers):
//       x @ [0,16384) | h0 @ [16384,24576) | h1 @ [0,4096) | h2 @ [16384,24576)

#define BATCH 4096

typedef _Float16 h4 __attribute__((ext_vector_type(4)));

__device__ __forceinline__ float fastrcp(float x) { return __builtin_amdgcn_rcpf(x); }
__device__ __forceinline__ _Float16 hrcp(_Float16 x) {
#if __has_builtin(__builtin_amdgcn_rcph)
    return __builtin_amdgcn_rcph(x);
#else
    return (_Float16)__builtin_amdgcn_rcpf((float)x);
#endif
}
__device__ __forceinline__ h4 splat(_Float16 s) { h4 v = {s, s, s, s}; return v; }

// ---------------- prep: fp16 prob table only ----------------
// probsH: [0,2048) L0 | [2048,3072) L1 | [3072,5120) L2 | [5120,9216) L3
__global__ __launch_bounds__(256) void prep_k(const float* __restrict__ w0,
                                              const float* __restrict__ w1,
                                              const float* __restrict__ w2,
                                              const float* __restrict__ w3,
                                              const int* __restrict__ is_train,
                                              h4* __restrict__ probsH) {
    const int g = blockIdx.x * 256 + threadIdx.x;   // grid 36 -> 9216 exact
    const float* w; int o;
    if (g < 2048)      { w = w0; o = g; }
    else if (g < 3072) { w = w1; o = g - 2048; }
    else if (g < 5120) { w = w2; o = g - 3072; }
    else               { w = w3; o = g - 5120; }
    float wv[4];
#pragma unroll
    for (int c = 0; c < 4; ++c) wv[c] = w[(o << 2) + c];
    float p[4];
    if (*is_train) {
        float m = fmaxf(fmaxf(wv[0], wv[1]), fmaxf(wv[2], wv[3]));
        float s = 0.0f;
#pragma unroll
        for (int c = 0; c < 4; ++c) { p[c] = __expf(wv[c] - m); s += p[c]; }
        float inv = fastrcp(s);
#pragma unroll
        for (int c = 0; c < 4; ++c) p[c] *= inv;
    } else {
        int a = 0; float best = wv[0];
#pragma unroll
        for (int c = 1; c < 4; ++c) if (wv[c] > best) { best = wv[c]; a = c; }
#pragma unroll
        for (int c = 0; c < 4; ++c) p[c] = (c == a) ? 1.0f : 0.0f;
    }
    probsH[g] = h4{(_Float16)p[0], (_Float16)p[1], (_Float16)p[2], (_Float16)p[3]};
}

// ---------------- chain state: 6 parallel reductions, packed fp16 ----------------
struct Chain { h4 mn, mx, De, Ne, Nc, Dc; };

__device__ __forceinline__ void chain_init(Chain& C, h4 v, h4 one, h4 two) {
    C.mn = v; C.mx = v; C.De = v;
    C.Ne = two - v; C.Nc = one + v; C.Dc = one - v;
}
__device__ __forceinline__ void chain_step(Chain& C, h4 v, h4 two) {
    C.mn = __builtin_elementwise_min(C.mn, v);
    C.mx = __builtin_elementwise_max(C.mx, v);
    C.De *= v;
    C.Ne *= (two - v);
    C.Nc += C.Nc * v;   // pk_fma: Nc *= (1+v)
    C.Dc -= C.Dc * v;   // pk_fma: Dc *= (1-v)
}
// combined-denominator finale: one rcp serves both ein and coe.
__device__ __forceinline__ h4 finale(const Chain& C, h4 P) {
    h4 s1 = C.Ne + C.De;        // [1, 257]
    h4 s2 = C.Nc + C.Dc;        // [1, 257]
    h4 d1 = C.Nc - C.Dc;        // [0, 256]
    h4 ss = s1 * s2;            // <= ~914: fp16-safe
    h4 r;
#pragma unroll
    for (int e = 0; e < 4; ++e) r[e] = hrcp(ss[e]);
    h4 t1 = (C.De + C.De) * s2; // 2*De*s2 <= 514
    h4 t2 = d1 * s1;            // <= 912
    h4 num = splat(P[2]) * t1 + splat(P[3]) * t2;
    return splat(P[0]) * C.mn + splat(P[1]) * C.mx + num * r;
}

// ---------------- single gate (L1) ----------------
__device__ __forceinline__ h4 gate1(const h4* __restrict__ rows,
                                    const int4* __restrict__ idx,
                                    const h4* __restrict__ probs, int o) {
    const int4 i0 = idx[o * 2], i1 = idx[o * 2 + 1];
    const h4 P = probs[o];
    h4 A[8];
    A[0] = rows[i0.x]; A[1] = rows[i0.y]; A[2] = rows[i0.z]; A[3] = rows[i0.w];
    A[4] = rows[i1.x]; A[5] = rows[i1.y]; A[6] = rows[i1.z]; A[7] = rows[i1.w];
    const h4 one = splat((_Float16)1.0f), two = splat((_Float16)2.0f);
    Chain C; chain_init(C, A[0], one, two);
#pragma unroll
    for (int c = 1; c < 8; ++c) chain_step(C, A[c], two);
    return finale(C, P);
}

// ---------------- paired gates (adjacent outputs o0, o0+1) ----------------
// 16 ds_read_b64 issued up front, two chains interleaved for ILP.
__device__ __forceinline__ void gate2(const h4* __restrict__ rows,
                                      const int4* __restrict__ idx,
                                      const h4* __restrict__ probs,
                                      int o0, h4& ra, h4& rb) {
    const int4 a0 = idx[o0 * 2],     a1 = idx[o0 * 2 + 1];
    const int4 b0 = idx[o0 * 2 + 2], b1 = idx[o0 * 2 + 3];
    const h4 PA = probs[o0], PB = probs[o0 + 1];
    h4 A[8], B[8];
    A[0] = rows[a0.x]; A[1] = rows[a0.y]; A[2] = rows[a0.z]; A[3] = rows[a0.w];
    A[4] = rows[a1.x]; A[5] = rows[a1.y]; A[6] = rows[a1.z]; A[7] = rows[a1.w];
    B[0] = rows[b0.x]; B[1] = rows[b0.y]; B[2] = rows[b0.z]; B[3] = rows[b0.w];
    B[4] = rows[b1.x]; B[5] = rows[b1.y]; B[6] = rows[b1.z]; B[7] = rows[b1.w];
    const h4 one = splat((_Float16)1.0f), two = splat((_Float16)2.0f);
    Chain CA, CB;
    chain_init(CA, A[0], one, two);
    chain_init(CB, B[0], one, two);
#pragma unroll
    for (int c = 1; c < 8; ++c) {
        chain_step(CA, A[c], two);
        chain_step(CB, B[c], two);
    }
    ra = finale(CA, PA);
    rb = finale(CB, PB);
}

struct alignas(16) H4x2 { h4 a, b; };

// ---------------- the fused network ----------------
// grid = 1024 (one block per 4-batch tile), block = 1024, 2 blocks/CU
__global__ __launch_bounds__(1024, 8) void ddlg_fused(const float* __restrict__ x,
                                                      const h4* __restrict__ probsH,
                                                      const int4* __restrict__ idx0,
                                                      const int4* __restrict__ idx1,
                                                      const int4* __restrict__ idx2,
                                                      const int4* __restrict__ idx3,
                                                      float* __restrict__ out) {
    __shared__ __align__(16) _Float16 lds[24576];   // 48 KB
    const int t  = threadIdx.x;
    const int b0 = blockIdx.x << 2;

    const h4* xl  = (const h4*)lds;                 // rows [0,4096)
    const h4* h0v = (const h4*)(lds + 16384);       // rows [0,2048)
    const h4* h1v = (const h4*)lds;                 // rows [0,1024) (over dead x)
    const h4* h2v = (const h4*)(lds + 16384);       // rows [0,2048) (over dead h0)

    // ---- stage x columns: thread owns j; 4 coalesced scalar loads -> b64 row ----
#pragma unroll
    for (int c = 0; c < 4; ++c) {
        const int j = (c << 10) + t;
        const float v0 = x[(size_t)(b0 + 0) * 4096 + j];
        const float v1 = x[(size_t)(b0 + 1) * 4096 + j];
        const float v2 = x[(size_t)(b0 + 2) * 4096 + j];
        const float v3 = x[(size_t)(b0 + 3) * 4096 + j];
        h4 hv;
        hv[0] = (_Float16)v0; hv[1] = (_Float16)v1;
        hv[2] = (_Float16)v2; hv[3] = (_Float16)v3;
        *(h4*)(lds + (j << 2)) = hv;    // stride-1 ds_write_b64: conflict-free
    }
    __syncthreads();

    // ---- L0: 4096 -> 2048, thread owns o = 2t, 2t+1 ----
    {
        h4 ra, rb;
        gate2(xl, idx0, probsH, 2 * t, ra, rb);
        *(H4x2*)(lds + 16384 + (t << 3)) = H4x2{ra, rb};   // rows 2t,2t+1: one b128
    }
    __syncthreads();

    // ---- L1: 2048 -> 1024, thread owns o = t ----
    {
        h4 r = gate1(h0v, idx1, probsH + 2048, t);
        *(h4*)(lds + (t << 2)) = r;
    }
    __syncthreads();

    // ---- L2: 1024 -> 2048, thread owns o = 2t, 2t+1 ----
    {
        h4 ra, rb;
        gate2(h1v, idx2, probsH + 3072, 2 * t, ra, rb);
        *(H4x2*)(lds + 16384 + (t << 3)) = H4x2{ra, rb};
    }
    __syncthreads();

    // ---- L3: 2048 -> 4096, thread owns o = 4t..4t+3; float4 stores ----
    {
        h4 r0, r1, r2, r3;
        gate2(h2v, idx3, probsH + 5120, 4 * t,     r0, r1);
        gate2(h2v, idx3, probsH + 5120, 4 * t + 2, r2, r3);
#pragma unroll
        for (int b = 0; b < 4; ++b) {
            float4 o4 = make_float4((float)r0[b], (float)r1[b],
                                    (float)r2[b], (float)r3[b]);
            *(float4*)(out + (size_t)(b0 + b) * 4096 + (t << 2)) = o4;
        }
    }
}

extern "C" void kernel_launch(void* const* d_in, const int* in_sizes, int n_in,
                              void* d_out, int out_size, void* d_ws, size_t ws_size,
                              hipStream_t stream) {
    const float* x        = (const float*)d_in[0];
    const float* w0       = (const float*)d_in[1];
    const float* w1       = (const float*)d_in[2];
    const float* w2       = (const float*)d_in[3];
    const float* w3       = (const float*)d_in[4];
    const int4*  idx0     = (const int4*)d_in[5];
    const int4*  idx1     = (const int4*)d_in[6];
    const int4*  idx2     = (const int4*)d_in[7];
    const int4*  idx3     = (const int4*)d_in[8];
    const int*   is_train = (const int*)d_in[9];
    float*       out      = (float*)d_out;

    // ws: probsH 9216*8B = 72 KB @0
    h4* probsH = (h4*)d_ws;

    prep_k<<<36, 256, 0, stream>>>(w0, w1, w2, w3, is_train, probsH);
    ddlg_fused<<<1024, 1024, 0, stream>>>(x, probsH, idx0, idx1, idx2, idx3, out);
}